// Round 13
// baseline (390.327 us; speedup 1.0000x reference)
//
#include <hip/hip_runtime.h>
#include <cstdint>
#include <cstddef>

// Problem constants (fixed by setup_inputs)
constexpr int kB  = 2;        // batch
constexpr int kQ  = 100;      // queries
constexpr int kN  = 200000;   // points
constexpr int kI  = 64;       // instances
constexpr int kC1 = 6;        // classes + 1 (no-object)
constexpr int kQP = 128;      // padded column count (cols >= kQ cost 1e30)

// ---------------------------------------------------------------------------
// prep: per-batch label histogram (cnt) + first occurrence index (firstIdx)
// ---------------------------------------------------------------------------
__global__ void prep_kernel(const int* __restrict__ labels,
                            int* __restrict__ cnt, int* __restrict__ firstIdx) {
  const int b = blockIdx.y;
  const int tid = threadIdx.x;
  __shared__ int lcnt[kI], lmin[kI];
  if (tid < kI) { lcnt[tid] = 0; lmin[tid] = 0x7FFFFFFF; }
  __syncthreads();
  for (int n = blockIdx.x * blockDim.x + tid; n < kN; n += gridDim.x * blockDim.x) {
    int l = labels[(size_t)b * kN + n] & (kI - 1);
    atomicAdd(&lcnt[l], 1);
    atomicMin(&lmin[l], n);
  }
  __syncthreads();
  if (tid < kI) {
    if (lcnt[tid]) atomicAdd(&cnt[b * kI + tid], lcnt[tid]);
    atomicMin(&firstIdx[b * kI + tid], lmin[tid]);
  }
}

// ---------------------------------------------------------------------------
// bucket v3 (proven r9-r12): segmented sums, ONE packed u64 LDS atomic per
// element: hi32 = fi (signed, scale 2^14), lo32 = pi. No carry lo->hi.
// ---------------------------------------------------------------------------
__global__ __launch_bounds__(1024) void bucket_kernel(
    const float* __restrict__ pm, const int* __restrict__ labels,
    const int* __restrict__ cnt,
    float* __restrict__ fS, float* __restrict__ pS,
    float* __restrict__ negTot, float* __restrict__ pTot,
    float* __restrict__ costT) {
  const int q = blockIdx.x, b = blockIdx.y;
  const int tid = threadIdx.x;
  const int w = tid >> 6;
  constexpr float kScale = 16384.0f;          // 2^14
  constexpr double kInv  = 1.0 / 16384.0;

  __shared__ unsigned long long lS[16][kI];   // per-wave packed (fi<<32)+pi
  ((unsigned long long*)lS)[tid] = 0ull;      // 16*64 == 1024
  __syncthreads();

  const float4* row4 = (const float4*)(pm + ((size_t)(b * kQ + q)) * kN);
  const int4*   lab4 = (const int4*)(labels + (size_t)b * kN);
  float negAcc = 0.f;
  constexpr int NV4 = kN / 4;

  for (int it = tid; it < NV4; it += 1024) {
    float4 xv = row4[it];
    int4   lv = lab4[it];
#define PROC(x_, l_) do {                                   \
      float x = (x_); int l = (l_) & (kI - 1);              \
      float xc = fminf(fmaxf(x, -60.f), 60.f);              \
      float t  = __expf(-xc);                               \
      float r  = 1.0f / (1.0f + t);   /* sigmoid(x) */      \
      float L  = __logf(1.0f + t);    /* softplus(-x) */    \
      float omp = t * r;              /* 1 - p */           \
      float pos = 0.25f * omp * omp * L;                    \
      float neg = 0.75f * r * r * (L + x);                  \
      int fi = __float2int_rn((pos - neg) * kScale);        \
      int pi = __float2int_rn(r * kScale);                  \
      unsigned long long pk =                               \
        (unsigned long long)(((long long)fi) << 32) +       \
        (unsigned long long)(unsigned int)pi;               \
      atomicAdd(&lS[w][l], pk);                             \
      negAcc += neg;                                        \
    } while (0)
    PROC(xv.x, lv.x); PROC(xv.y, lv.y); PROC(xv.z, lv.z); PROC(xv.w, lv.w);
#undef PROC
  }
  __syncthreads();

  __shared__ float ffS[kI], fpS[kI];
  if (tid < kI) {
    long long fsum = 0, psum = 0;
    for (int ww = 0; ww < 16; ++ww) {
      unsigned long long s = lS[ww][tid];
      fsum += (int)(s >> 32);                 // two's-complement hi word
      psum += (long long)(s & 0xFFFFFFFFull);
    }
    ffS[tid] = (float)((double)fsum * kInv);
    fpS[tid] = (float)((double)psum * kInv);
  }
  for (int off = 32; off; off >>= 1) negAcc += __shfl_down(negAcc, off);
  __shared__ float wsum[16];
  if ((tid & 63) == 0) wsum[w] = negAcc;
  __syncthreads();
  __shared__ float s_negTot, s_pTot;
  if (tid == 0) {
    float s = 0.f;
    for (int ww = 0; ww < 16; ++ww) s += wsum[ww];
    s_negTot = s;
  }
  if (tid < kI) {
    float vv = fpS[tid];
    for (int off = 32; off; off >>= 1) vv += __shfl_down(vv, off);
    if (tid == 0) s_pTot = vv;
  }
  __syncthreads();

  if (tid < kI) {
    float f = ffS[tid], pp = fpS[tid];
    int bq = b * kQ + q;
    fS[(size_t)bq * kI + tid] = f;
    pS[(size_t)bq * kI + tid] = pp;
    float cf = (f + s_negTot) * (1.0f / kN);
    float cd = 1.0f - (2.0f * pp + 1.0f) / (s_pTot + (float)cnt[b * kI + tid] + 1.0f);
    costT[(size_t)(b * kI + tid) * kQ + q] = cf + cd;
    if (tid == 0) { negTot[bq] = s_negTot; pTot[bq] = s_pTot; }
  }
}

// ---------------------------------------------------------------------------
// Hungarian v12 — r12-passing machinery with exec-mask overhead stripped:
//  * columns padded to 128 (pad cost 1e30, never selectable since <=64 of
//    100 real columns are ever used) => zero s1v divergence, uniform slots.
//  * branchless dual/state updates (v_cndmask instead of exec toggles).
//  * augrowred selection moved to the f32 packed path (like SAP's, which
//    passed r12) with EXACT f64 readback of min1 AND min2 from owner lanes.
//    Selection by fminf on float VALUES (not bit order) => no >=0 needed.
// CS lesson stands (v5-v7, v10): no dual warm starts; v<0 only on claimed
// (forever-matched) columns.
// ---------------------------------------------------------------------------
template<int CTRL>
__device__ __forceinline__ int dpp_mov(int x) {
  return __builtin_amdgcn_update_dpp(x, x, CTRL, 0xF, 0xF, false);
}
template<int CTRL>
__device__ __forceinline__ float dpp_minf(float a) {
  int o = dpp_mov<CTRL>(__float_as_int(a));
  return fminf(a, __int_as_float(o));
}
__device__ __forceinline__ double rl64(double x, int l) {
  int lo = __builtin_amdgcn_readlane(__double2loint(x), l);
  int hi = __builtin_amdgcn_readlane(__double2hiint(x), l);
  return __hiloint2double(hi, lo);
}
__device__ __forceinline__ float rlf(float x, int l) {
  return __int_as_float(__builtin_amdgcn_readlane(__float_as_int(x), l));
}
__device__ __forceinline__ float packF(float v, int cid) {
  int bb = __float_as_int(v);
  bb = (bb & ~0x7F) | cid;
  return __int_as_float(bb);
}
// two-smallest combine on packed f32 (value order; ids ride in low bits)
__device__ __forceinline__ void comb2f(float& m1, float& m2, float o1, float o2) {
  float lo = fminf(m1, o1);
  float hi = fmaxf(m1, o1);
  m2 = fminf(hi, fminf(m2, o2));
  m1 = lo;
}
template<int CTRL>
__device__ __forceinline__ void dpp_comb2f(float& m1, float& m2) {
  float o1 = __int_as_float(dpp_mov<CTRL>(__float_as_int(m1)));
  float o2 = __int_as_float(dpp_mov<CTRL>(__float_as_int(m2)));
  comb2f(m1, m2, o1, o2);
}

__global__ void hungarian_kernel(const float* __restrict__ costT,
                                 int* __restrict__ idx_q) {
  const int b = blockIdx.x;
  const int lane = threadIdx.x;  // 64 threads = 1 wave
  __shared__ float costL[kI * kQP];
  for (int t = lane; t < kI * kQP; t += 64) {
    int row = t >> 7, col = t & (kQP - 1);
    costL[t] = (col < kQ) ? costT[(size_t)b * kI * kQ + row * kQ + col] : 1e30f;
  }
  __syncthreads();

  const double INF = 1e18;
  double v0 = 0.0, v1 = 0.0;     // v[col lane], v[col lane+64]
  int p0 = 0, p1 = 0;            // matched row (1-based) of cols lane, lane+64
  // col ids are 0-based throughout: cid = lane (slot0) or lane+64 (slot1)

  // --- JV greedy init: u[row]=row min; claim free argmin columns ----------
  double m = INF; int jm = 0;
  for (int k = 0; k < kQ; ++k) {
    double c = (double)costL[lane * kQP + k];
    if (c < m) { m = c; jm = k; }            // first-index min
  }
  double u_r = m;                             // u[lane+1]
  unsigned long long rowM = 0ull;
  for (int r = 0; r < kI; ++r) {
    int jmr = __builtin_amdgcn_readlane(jm, r);   // 0..99
    int curp = (jmr < 64) ? __builtin_amdgcn_readlane(p0, jmr)
                          : __builtin_amdgcn_readlane(p1, jmr - 64);
    if (curp == 0) {
      bool m0 = (jmr < 64) && (lane == jmr);
      bool m1b = (jmr >= 64) && (lane == jmr - 64);
      p0 = m0 ? r + 1 : p0;
      p1 = m1b ? r + 1 : p1;
      rowM |= 1ull << r;
    }
  }

  // --- LAPJV augmenting row reduction (2 passes; f32 select + exact f64) ---
  unsigned long long pool = ~rowM;            // unmatched rows (bit r = row r+1)
  unsigned long long leftover = 0ull;
  for (int pass = 0; pass < 2; ++pass) {
    unsigned long long next = 0ull;
    unsigned long long cur = pool;
    while (cur) {
      int i = __builtin_ctzll(cur) + 1;       // row, 1-based
      cur &= cur - 1;
      const float* crow = &costL[(i - 1) * kQP];
      double e0 = (double)crow[lane] - v0;
      double e1 = (double)crow[lane + 64] - v1;   // padded cols ~1e30
      float pf0 = packF((float)e0, lane);
      float pf1 = packF((float)e1, lane + 64);
      float m1 = fminf(pf0, pf1), m2 = fmaxf(pf0, pf1);
      dpp_comb2f<0xB1>(m1, m2);               // xor 1
      dpp_comb2f<0x4E>(m1, m2);               // xor 2
      dpp_comb2f<0x141>(m1, m2);              // xor 4
      dpp_comb2f<0x140>(m1, m2);              // xor 8
      float a1 = rlf(m1, 0),  a2 = rlf(m2, 0);
      { float b1 = rlf(m1, 16), b2 = rlf(m2, 16); comb2f(a1, a2, b1, b2); }
      { float b1 = rlf(m1, 32), b2 = rlf(m2, 32); comb2f(a1, a2, b1, b2); }
      { float b1 = rlf(m1, 48), b2 = rlf(m2, 48); comb2f(a1, a2, b1, b2); }
      int cid1 = __builtin_amdgcn_readfirstlane(__float_as_int(a1) & 0x7F);
      int cid2 = __builtin_amdgcn_readfirstlane(__float_as_int(a2) & 0x7F);
      int L1 = cid1 & 63; bool sW = cid1 >= 64;
      int L2 = cid2 & 63; bool sW2 = cid2 >= 64;
      double min1 = sW  ? rl64(e1, L1) : rl64(e0, L1);   // EXACT values
      double min2 = sW2 ? rl64(e1, L2) : rl64(e0, L2);
      double dv = min2 - min1;
      u_r = (lane == i - 1) ? min2 : u_r;     // u[i] = second minimum
      int i0 = sW ? __builtin_amdgcn_readlane(p1, L1)
                  : __builtin_amdgcn_readlane(p0, L1);
      bool mine0 = (!sW) && (lane == L1);
      bool mine1 = sW && (lane == L1);
      p0 = mine0 ? i : p0;  v0 -= mine0 ? dv : 0.0;
      p1 = mine1 ? i : p1;  v1 -= mine1 ? dv : 0.0;
      if (i0 != 0) {                          // kicked row -> later pass / SAP
        if (pass == 0) next |= 1ull << (i0 - 1);
        else           leftover |= 1ull << (i0 - 1);
      }
    }
    pool = next;
  }
  leftover |= pool;                           // (pool empty after pass 1)

  // --- exact SAP for leftover rows (branchless round) ----------------------
  const float SENT = packF(1e30f, 127);
  for (int i = 1; i <= kI; ++i) {
    if (!((leftover >> (i - 1)) & 1ull)) continue;
    double minv0 = INF, minv1 = INF;
    int way0 = 0, way1 = 0;
    bool used0 = false, used1 = false;
    bool onpath = (lane == i - 1);
    int i0 = i, j0 = 0, j1 = 0;
    float c0 = costL[(i0 - 1) * kQP + lane];
    float c1 = costL[(i0 - 1) * kQP + lane + 64];
    for (int guard = 0; guard < 2 * kQ; ++guard) {
      double ui0 = rl64(u_r, i0 - 1);
      double cur0 = (double)c0 - ui0 - v0;
      bool up0 = (!used0) && (cur0 < minv0);
      minv0 = up0 ? cur0 : minv0;
      way0  = up0 ? j0 : way0;
      double cur1 = (double)c1 - ui0 - v1;
      bool up1 = (!used1) && (cur1 < minv1);
      minv1 = up1 ? cur1 : minv1;
      way1  = up1 ? j0 : way1;
      // f32-packed argmin butterfly (selection only)
      float pk0 = used0 ? SENT : packF((float)minv0, lane);
      float pk1 = used1 ? SENT : packF((float)minv1, lane + 64);
      float bm = fminf(pk0, pk1);
      bm = dpp_minf<0xB1>(bm);    // xor 1
      bm = dpp_minf<0x4E>(bm);    // xor 2
      bm = dpp_minf<0x141>(bm);   // xor 4
      bm = dpp_minf<0x140>(bm);   // xor 8
      float g = fminf(fminf(rlf(bm, 0), rlf(bm, 16)),
                      fminf(rlf(bm, 32), rlf(bm, 48)));
      int cid = __builtin_amdgcn_readfirstlane(__float_as_int(g) & 0x7F);
      const int  L = cid & 63;
      const bool s = cid >= 64;
      double delta = s ? rl64(minv1, L) : rl64(minv0, L);   // EXACT value
      int r1 = s ? __builtin_amdgcn_readlane(p1, L)
                 : __builtin_amdgcn_readlane(p0, L);
      // prefetch next row while updating duals
      int i0n = (r1 > 0) ? r1 : 1;
      float c0n = costL[(i0n - 1) * kQP + lane];
      float c1n = costL[(i0n - 1) * kQP + lane + 64];

      u_r  += onpath ? delta : 0.0;
      v0    -= used0 ? delta : 0.0;
      minv0 -= used0 ? 0.0 : delta;
      v1    -= used1 ? delta : 0.0;
      minv1 -= used1 ? 0.0 : delta;
      used0 = used0 || ((!s) && (lane == L));
      used1 = used1 || (s && (lane == L));
      j1 = cid + 1;                 // 1-based for augment chain

      if (r1 == 0) break;           // free column reached
      onpath = onpath || (lane == r1 - 1);
      i0 = r1;
      j0 = j1;
      c0 = c0n;
      c1 = c1n;
    }
    // augment along way-chain (all indices/values uniform)
    int jc = j1;
    while (jc) {
      int jw = (jc <= 64) ? __builtin_amdgcn_readlane(way0, jc - 1)
                          : __builtin_amdgcn_readlane(way1, jc - 65);
      int pw;
      if (jw == 0)       pw = i;
      else if (jw <= 64) pw = __builtin_amdgcn_readlane(p0, jw - 1);
      else               pw = __builtin_amdgcn_readlane(p1, jw - 65);
      bool w0 = (jc <= 64) && (lane == jc - 1);
      bool w1 = (jc > 64) && (lane == jc - 65);
      p0 = w0 ? pw : p0;
      p1 = w1 ? pw : p1;
      jc = jw;
    }
  }
  if (p0 > 0) idx_q[b * kI + (p0 - 1)] = lane;
  if (lane < kQ - 64 && p1 > 0) idx_q[b * kI + (p1 - 1)] = lane + 64;
}

// ---------------------------------------------------------------------------
// final loss from bucket sums + matching
// ---------------------------------------------------------------------------
__device__ __forceinline__ float reduce128(float v, float* scratch, int tid) {
  for (int off = 32; off; off >>= 1) v += __shfl_down(v, off);
  __syncthreads();
  if ((tid & 63) == 0) scratch[tid >> 6] = v;
  __syncthreads();
  return scratch[0] + scratch[1];
}

__global__ void loss_kernel(const float* __restrict__ logits, const int* __restrict__ seg,
                            const float* __restrict__ fS, const float* __restrict__ pS,
                            const float* __restrict__ negTot, const float* __restrict__ pTot,
                            const int* __restrict__ cnt, const int* __restrict__ firstIdx,
                            const int* __restrict__ idx_q, float* __restrict__ out) {
  const int tid = threadIdx.x;  // 128
  __shared__ float lse[kQ];
  __shared__ int matched[kQ];
  __shared__ float scratch[2];
  float total = 0.f;
  for (int b = 0; b < kB; ++b) {
    if (tid < kQ) {
      const float* lr = logits + (size_t)(b * kQ + tid) * kC1;
      float m = lr[0];
#pragma unroll
      for (int c = 1; c < kC1; ++c) m = fmaxf(m, lr[c]);
      float s = 0.f;
#pragma unroll
      for (int c = 0; c < kC1; ++c) s += __expf(lr[c] - m);
      lse[tid] = m + __logf(s);
      matched[tid] = 0;
    }
    __syncthreads();
    if (tid < kI) matched[idx_q[b * kI + tid]] = 1;
    __syncthreads();

    float fo = 0.f, di = 0.f, cm = 0.f, no = 0.f, nu = 0.f;
    if (tid < kI) {
      int qi = idx_q[b * kI + tid];
      int bq = b * kQ + qi;
      float f = fS[(size_t)bq * kI + tid];
      fo = f + negTot[bq];
      float pp = pS[(size_t)bq * kI + tid];
      di = 1.f - (2.f * pp + 1.f) / (pTot[bq] + (float)cnt[b * kI + tid] + 1.f);
      int fi = firstIdx[b * kI + tid];
      fi = fi < kN ? fi : kN - 1;
      int ci = seg[(size_t)b * kN + fi];
      ci = ci < 0 ? 0 : (ci > kC1 - 2 ? kC1 - 2 : ci);  // clip(·,0,C-1)
      cm = logits[(size_t)bq * kC1 + ci] - lse[qi];
    }
    if (tid < kQ && !matched[tid]) {
      no = logits[(size_t)(b * kQ + tid) * kC1 + (kC1 - 1)] - lse[tid];
      nu = 1.f;
    }
    float foS = reduce128(fo, scratch, tid);
    float diS = reduce128(di, scratch, tid);
    float cmS = reduce128(cm, scratch, tid);
    float noS = reduce128(no, scratch, tid);
    float nuS = reduce128(nu, scratch, tid);

    float focal = foS / ((float)kI * (float)kN);
    float dice  = diS / (float)kI;
    float cem   = -cmS / (float)kI;
    float cen   = -noS / fmaxf(nuS, 1.f);
    total += focal + dice + 2.0f * cem + 0.1f * cen;
    __syncthreads();
  }
  if (tid == 0) out[0] = total * (1.0f / kB);
}

// ---------------------------------------------------------------------------
extern "C" void kernel_launch(void* const* d_in, const int* in_sizes, int n_in,
                              void* d_out, int out_size, void* d_ws, size_t ws_size,
                              hipStream_t stream) {
  const float* pm     = (const float*)d_in[0];  // [B,Q,N]
  const float* logits = (const float*)d_in[1];  // [B,Q,C1]
  const int*   labels = (const int*)d_in[2];    // [B,N]
  const int*   seg    = (const int*)d_in[3];    // [B,N]

  char* w = (char*)d_ws;
  float* fS       = (float*)w; w += (size_t)kB * kQ * kI * 4;
  float* pS       = (float*)w; w += (size_t)kB * kQ * kI * 4;
  float* negTot   = (float*)w; w += (size_t)kB * kQ * 4;
  float* pTot     = (float*)w; w += (size_t)kB * kQ * 4;
  float* costT    = (float*)w; w += (size_t)kB * kI * kQ * 4;
  int*   cnt      = (int*)w;   w += (size_t)kB * kI * 4;
  int*   firstIdx = (int*)w;   w += (size_t)kB * kI * 4;
  int*   idx_q    = (int*)w;   w += (size_t)kB * kI * 4;

  (void)hipMemsetAsync(cnt, 0, (size_t)kB * kI * 4, stream);
  (void)hipMemsetAsync(firstIdx, 0x7F, (size_t)kB * kI * 4, stream);

  prep_kernel<<<dim3(32, kB), 256, 0, stream>>>(labels, cnt, firstIdx);
  bucket_kernel<<<dim3(kQ, kB), 1024, 0, stream>>>(pm, labels, cnt, fS, pS,
                                                   negTot, pTot, costT);
  hungarian_kernel<<<kB, 64, 0, stream>>>(costT, idx_q);
  loss_kernel<<<1, 128, 0, stream>>>(logits, seg, fS, pS, negTot, pTot,
                                     cnt, firstIdx, idx_q, (float*)d_out);
}

// Round 14
// 371.781 us; speedup vs baseline: 1.0499x; 1.0499x over previous
//
#include <hip/hip_runtime.h>
#include <cstdint>
#include <cstddef>

// Problem constants (fixed by setup_inputs)
constexpr int kB  = 2;        // batch
constexpr int kQ  = 100;      // queries
constexpr int kN  = 200000;   // points
constexpr int kI  = 64;       // instances
constexpr int kC1 = 6;        // classes + 1 (no-object)
constexpr int kQP = 128;      // padded column count (cols >= kQ cost 1e30)

// ---------------------------------------------------------------------------
// prep: per-batch label histogram (cnt) + first occurrence index (firstIdx)
// ---------------------------------------------------------------------------
__global__ void prep_kernel(const int* __restrict__ labels,
                            int* __restrict__ cnt, int* __restrict__ firstIdx) {
  const int b = blockIdx.y;
  const int tid = threadIdx.x;
  __shared__ int lcnt[kI], lmin[kI];
  if (tid < kI) { lcnt[tid] = 0; lmin[tid] = 0x7FFFFFFF; }
  __syncthreads();
  for (int n = blockIdx.x * blockDim.x + tid; n < kN; n += gridDim.x * blockDim.x) {
    int l = labels[(size_t)b * kN + n] & (kI - 1);
    atomicAdd(&lcnt[l], 1);
    atomicMin(&lmin[l], n);
  }
  __syncthreads();
  if (tid < kI) {
    if (lcnt[tid]) atomicAdd(&cnt[b * kI + tid], lcnt[tid]);
    atomicMin(&firstIdx[b * kI + tid], lmin[tid]);
  }
}

// ---------------------------------------------------------------------------
// bucket v3 (proven r9-r13): segmented sums, ONE packed u64 LDS atomic per
// element: hi32 = fi (signed, scale 2^14), lo32 = pi. No carry lo->hi.
// ---------------------------------------------------------------------------
__global__ __launch_bounds__(1024) void bucket_kernel(
    const float* __restrict__ pm, const int* __restrict__ labels,
    const int* __restrict__ cnt,
    float* __restrict__ fS, float* __restrict__ pS,
    float* __restrict__ negTot, float* __restrict__ pTot,
    float* __restrict__ costT) {
  const int q = blockIdx.x, b = blockIdx.y;
  const int tid = threadIdx.x;
  const int w = tid >> 6;
  constexpr float kScale = 16384.0f;          // 2^14
  constexpr double kInv  = 1.0 / 16384.0;

  __shared__ unsigned long long lS[16][kI];   // per-wave packed (fi<<32)+pi
  ((unsigned long long*)lS)[tid] = 0ull;      // 16*64 == 1024
  __syncthreads();

  const float4* row4 = (const float4*)(pm + ((size_t)(b * kQ + q)) * kN);
  const int4*   lab4 = (const int4*)(labels + (size_t)b * kN);
  float negAcc = 0.f;
  constexpr int NV4 = kN / 4;

  for (int it = tid; it < NV4; it += 1024) {
    float4 xv = row4[it];
    int4   lv = lab4[it];
#define PROC(x_, l_) do {                                   \
      float x = (x_); int l = (l_) & (kI - 1);              \
      float xc = fminf(fmaxf(x, -60.f), 60.f);              \
      float t  = __expf(-xc);                               \
      float r  = 1.0f / (1.0f + t);   /* sigmoid(x) */      \
      float L  = __logf(1.0f + t);    /* softplus(-x) */    \
      float omp = t * r;              /* 1 - p */           \
      float pos = 0.25f * omp * omp * L;                    \
      float neg = 0.75f * r * r * (L + x);                  \
      int fi = __float2int_rn((pos - neg) * kScale);        \
      int pi = __float2int_rn(r * kScale);                  \
      unsigned long long pk =                               \
        (unsigned long long)(((long long)fi) << 32) +       \
        (unsigned long long)(unsigned int)pi;               \
      atomicAdd(&lS[w][l], pk);                             \
      negAcc += neg;                                        \
    } while (0)
    PROC(xv.x, lv.x); PROC(xv.y, lv.y); PROC(xv.z, lv.z); PROC(xv.w, lv.w);
#undef PROC
  }
  __syncthreads();

  __shared__ float ffS[kI], fpS[kI];
  if (tid < kI) {
    long long fsum = 0, psum = 0;
    for (int ww = 0; ww < 16; ++ww) {
      unsigned long long s = lS[ww][tid];
      fsum += (int)(s >> 32);                 // two's-complement hi word
      psum += (long long)(s & 0xFFFFFFFFull);
    }
    ffS[tid] = (float)((double)fsum * kInv);
    fpS[tid] = (float)((double)psum * kInv);
  }
  for (int off = 32; off; off >>= 1) negAcc += __shfl_down(negAcc, off);
  __shared__ float wsum[16];
  if ((tid & 63) == 0) wsum[w] = negAcc;
  __syncthreads();
  __shared__ float s_negTot, s_pTot;
  if (tid == 0) {
    float s = 0.f;
    for (int ww = 0; ww < 16; ++ww) s += wsum[ww];
    s_negTot = s;
  }
  if (tid < kI) {
    float vv = fpS[tid];
    for (int off = 32; off; off >>= 1) vv += __shfl_down(vv, off);
    if (tid == 0) s_pTot = vv;
  }
  __syncthreads();

  if (tid < kI) {
    float f = ffS[tid], pp = fpS[tid];
    int bq = b * kQ + q;
    fS[(size_t)bq * kI + tid] = f;
    pS[(size_t)bq * kI + tid] = pp;
    float cf = (f + s_negTot) * (1.0f / kN);
    float cd = 1.0f - (2.0f * pp + 1.0f) / (s_pTot + (float)cnt[b * kI + tid] + 1.0f);
    costT[(size_t)(b * kI + tid) * kQ + q] = cf + cd;
    if (tid == 0) { negTot[bq] = s_negTot; pTot[bq] = s_pTot; }
  }
}

// ---------------------------------------------------------------------------
// Hungarian v13 — r13 machinery with FULL-f32 SAP round:
//  * minv kept packed (f32 value, low-7 mantissa bits = col id); delta =
//    packed min with id masked -> ZERO readlanes for delta (was 2).
//  * duals u,v in f32 for the SAP phase (converted once after augrowred);
//    ui0 = one rlf, prefetched at round end.
//  * all lanes operate on the same quantized lattice (uniform masked delta)
//    => deterministic, uniform updates. Perturbation <= 2^-16 rel, same
//    class as r12/r13's PASSING f32 selection (margins ~1e-3).
// augrowred unchanged from r13 (f32 select + exact f64 readback; proven).
// CS lesson stands (v5-v7, v10): no dual warm starts.
// ---------------------------------------------------------------------------
template<int CTRL>
__device__ __forceinline__ int dpp_mov(int x) {
  return __builtin_amdgcn_update_dpp(x, x, CTRL, 0xF, 0xF, false);
}
template<int CTRL>
__device__ __forceinline__ float dpp_minf(float a) {
  int o = dpp_mov<CTRL>(__float_as_int(a));
  return fminf(a, __int_as_float(o));
}
__device__ __forceinline__ double rl64(double x, int l) {
  int lo = __builtin_amdgcn_readlane(__double2loint(x), l);
  int hi = __builtin_amdgcn_readlane(__double2hiint(x), l);
  return __hiloint2double(hi, lo);
}
__device__ __forceinline__ float rlf(float x, int l) {
  return __int_as_float(__builtin_amdgcn_readlane(__float_as_int(x), l));
}
__device__ __forceinline__ float packF(float v, int cid) {
  int bb = __float_as_int(v);
  bb = (bb & ~0x7F) | cid;
  return __int_as_float(bb);
}
__device__ __forceinline__ float maskF(float v) {          // id bits -> 0
  return __int_as_float(__float_as_int(v) & ~0x7F);
}
// two-smallest combine on packed f32 (value order; ids ride in low bits)
__device__ __forceinline__ void comb2f(float& m1, float& m2, float o1, float o2) {
  float lo = fminf(m1, o1);
  float hi = fmaxf(m1, o1);
  m2 = fminf(hi, fminf(m2, o2));
  m1 = lo;
}
template<int CTRL>
__device__ __forceinline__ void dpp_comb2f(float& m1, float& m2) {
  float o1 = __int_as_float(dpp_mov<CTRL>(__float_as_int(m1)));
  float o2 = __int_as_float(dpp_mov<CTRL>(__float_as_int(m2)));
  comb2f(m1, m2, o1, o2);
}

__global__ void hungarian_kernel(const float* __restrict__ costT,
                                 int* __restrict__ idx_q) {
  const int b = blockIdx.x;
  const int lane = threadIdx.x;  // 64 threads = 1 wave
  __shared__ float costL[kI * kQP];
  for (int t = lane; t < kI * kQP; t += 64) {
    int row = t >> 7, col = t & (kQP - 1);
    costL[t] = (col < kQ) ? costT[(size_t)b * kI * kQ + row * kQ + col] : 1e30f;
  }
  __syncthreads();

  const double INF = 1e18;
  double v0 = 0.0, v1 = 0.0;     // v[col lane], v[col lane+64]
  int p0 = 0, p1 = 0;            // matched row (1-based) of cols lane, lane+64

  // --- JV greedy init: u[row]=row min; claim free argmin columns ----------
  double m = INF; int jm = 0;
  for (int k = 0; k < kQ; ++k) {
    double c = (double)costL[lane * kQP + k];
    if (c < m) { m = c; jm = k; }            // first-index min
  }
  double u_r = m;                             // u[lane+1]
  unsigned long long rowM = 0ull;
  for (int r = 0; r < kI; ++r) {
    int jmr = __builtin_amdgcn_readlane(jm, r);   // 0..99
    int curp = (jmr < 64) ? __builtin_amdgcn_readlane(p0, jmr)
                          : __builtin_amdgcn_readlane(p1, jmr - 64);
    if (curp == 0) {
      bool m0 = (jmr < 64) && (lane == jmr);
      bool m1b = (jmr >= 64) && (lane == jmr - 64);
      p0 = m0 ? r + 1 : p0;
      p1 = m1b ? r + 1 : p1;
      rowM |= 1ull << r;
    }
  }

  // --- LAPJV augmenting row reduction (2 passes; f32 select + exact f64) ---
  unsigned long long pool = ~rowM;            // unmatched rows (bit r = row r+1)
  unsigned long long leftover = 0ull;
  for (int pass = 0; pass < 2; ++pass) {
    unsigned long long next = 0ull;
    unsigned long long cur = pool;
    while (cur) {
      int i = __builtin_ctzll(cur) + 1;       // row, 1-based
      cur &= cur - 1;
      const float* crow = &costL[(i - 1) * kQP];
      double e0 = (double)crow[lane] - v0;
      double e1 = (double)crow[lane + 64] - v1;   // padded cols ~1e30
      float pf0 = packF((float)e0, lane);
      float pf1 = packF((float)e1, lane + 64);
      float m1 = fminf(pf0, pf1), m2 = fmaxf(pf0, pf1);
      dpp_comb2f<0xB1>(m1, m2);               // xor 1
      dpp_comb2f<0x4E>(m1, m2);               // xor 2
      dpp_comb2f<0x141>(m1, m2);              // xor 4
      dpp_comb2f<0x140>(m1, m2);              // xor 8
      float a1 = rlf(m1, 0),  a2 = rlf(m2, 0);
      { float b1 = rlf(m1, 16), b2 = rlf(m2, 16); comb2f(a1, a2, b1, b2); }
      { float b1 = rlf(m1, 32), b2 = rlf(m2, 32); comb2f(a1, a2, b1, b2); }
      { float b1 = rlf(m1, 48), b2 = rlf(m2, 48); comb2f(a1, a2, b1, b2); }
      int cid1 = __builtin_amdgcn_readfirstlane(__float_as_int(a1) & 0x7F);
      int cid2 = __builtin_amdgcn_readfirstlane(__float_as_int(a2) & 0x7F);
      int L1 = cid1 & 63; bool sW = cid1 >= 64;
      int L2 = cid2 & 63; bool sW2 = cid2 >= 64;
      double min1 = sW  ? rl64(e1, L1) : rl64(e0, L1);   // EXACT values
      double min2 = sW2 ? rl64(e1, L2) : rl64(e0, L2);
      double dv = min2 - min1;
      u_r = (lane == i - 1) ? min2 : u_r;     // u[i] = second minimum
      int i0 = sW ? __builtin_amdgcn_readlane(p1, L1)
                  : __builtin_amdgcn_readlane(p0, L1);
      bool mine0 = (!sW) && (lane == L1);
      bool mine1 = sW && (lane == L1);
      p0 = mine0 ? i : p0;  v0 -= mine0 ? dv : 0.0;
      p1 = mine1 ? i : p1;  v1 -= mine1 ? dv : 0.0;
      if (i0 != 0) {                          // kicked row -> later pass / SAP
        if (pass == 0) next |= 1ull << (i0 - 1);
        else           leftover |= 1ull << (i0 - 1);
      }
    }
    pool = next;
  }
  leftover |= pool;                           // (pool empty after pass 1)

  // --- exact SAP for leftover rows (full-f32 packed round) ------------------
  const float SENT = packF(1e30f, 127);
  float u_f  = (float)u_r;
  float v0f  = (float)v0;
  float v1f  = (float)v1;
  for (int i = 1; i <= kI; ++i) {
    if (!((leftover >> (i - 1)) & 1ull)) continue;
    float minv0 = SENT, minv1 = SENT;   // packed (value | col id)
    int way0 = 0, way1 = 0;
    bool used0 = false, used1 = false;
    bool onpath = (lane == i - 1);
    int j0 = 0, j1 = 0;
    float c0 = costL[(i - 1) * kQP + lane];
    float c1 = costL[(i - 1) * kQP + lane + 64];
    float ui0 = rlf(u_f, i - 1);
    for (int guard = 0; guard < 2 * kQ; ++guard) {
      float pk0 = packF(c0 - ui0 - v0f, lane);
      bool up0 = (!used0) && (pk0 < minv0);
      minv0 = up0 ? pk0 : minv0;
      way0  = up0 ? j0 : way0;
      float pk1 = packF(c1 - ui0 - v1f, lane + 64);
      bool up1 = (!used1) && (pk1 < minv1);
      minv1 = up1 ? pk1 : minv1;
      way1  = up1 ? j0 : way1;
      // argmin butterfly on packed values (used slots already SENT)
      float bm = fminf(minv0, minv1);
      bm = dpp_minf<0xB1>(bm);    // xor 1
      bm = dpp_minf<0x4E>(bm);    // xor 2
      bm = dpp_minf<0x141>(bm);   // xor 4
      bm = dpp_minf<0x140>(bm);   // xor 8
      float g = fminf(fminf(rlf(bm, 0), rlf(bm, 16)),
                      fminf(rlf(bm, 32), rlf(bm, 48)));
      int gi = __builtin_amdgcn_readfirstlane(__float_as_int(g));
      int cid = gi & 0x7F;
      float delta = __int_as_float(gi & ~0x7F);   // quantized min value
      const int  L = cid & 63;
      const bool s = cid >= 64;
      int r1 = s ? __builtin_amdgcn_readlane(p1, L)
                 : __builtin_amdgcn_readlane(p0, L);
      // prefetch next row while updating duals
      int i0n = (r1 > 0) ? r1 : 1;
      float c0n = costL[(i0n - 1) * kQP + lane];
      float c1n = costL[(i0n - 1) * kQP + lane + 64];

      u_f += onpath ? delta : 0.f;
      v0f -= used0 ? delta : 0.f;
      v1f -= used1 ? delta : 0.f;
      minv0 = used0 ? minv0 : packF(maskF(minv0) - delta, lane);
      minv1 = used1 ? minv1 : packF(maskF(minv1) - delta, lane + 64);
      bool w0 = (!s) && (lane == L);
      bool w1 = s && (lane == L);
      used0 = used0 || w0;
      used1 = used1 || w1;
      minv0 = w0 ? SENT : minv0;
      minv1 = w1 ? SENT : minv1;
      j1 = cid + 1;                 // 1-based for augment chain

      if (r1 == 0) break;           // free column reached
      onpath = onpath || (lane == r1 - 1);
      ui0 = rlf(u_f, r1 - 1);       // prefetched for next round
      j0 = j1;
      c0 = c0n;
      c1 = c1n;
    }
    // augment along way-chain (all indices/values uniform)
    int jc = j1;
    while (jc) {
      int jw = (jc <= 64) ? __builtin_amdgcn_readlane(way0, jc - 1)
                          : __builtin_amdgcn_readlane(way1, jc - 65);
      int pw;
      if (jw == 0)       pw = i;
      else if (jw <= 64) pw = __builtin_amdgcn_readlane(p0, jw - 1);
      else               pw = __builtin_amdgcn_readlane(p1, jw - 65);
      bool w0 = (jc <= 64) && (lane == jc - 1);
      bool w1 = (jc > 64) && (lane == jc - 65);
      p0 = w0 ? pw : p0;
      p1 = w1 ? pw : p1;
      jc = jw;
    }
  }
  if (p0 > 0) idx_q[b * kI + (p0 - 1)] = lane;
  if (lane < kQ - 64 && p1 > 0) idx_q[b * kI + (p1 - 1)] = lane + 64;
}

// ---------------------------------------------------------------------------
// final loss from bucket sums + matching
// ---------------------------------------------------------------------------
__device__ __forceinline__ float reduce128(float v, float* scratch, int tid) {
  for (int off = 32; off; off >>= 1) v += __shfl_down(v, off);
  __syncthreads();
  if ((tid & 63) == 0) scratch[tid >> 6] = v;
  __syncthreads();
  return scratch[0] + scratch[1];
}

__global__ void loss_kernel(const float* __restrict__ logits, const int* __restrict__ seg,
                            const float* __restrict__ fS, const float* __restrict__ pS,
                            const float* __restrict__ negTot, const float* __restrict__ pTot,
                            const int* __restrict__ cnt, const int* __restrict__ firstIdx,
                            const int* __restrict__ idx_q, float* __restrict__ out) {
  const int tid = threadIdx.x;  // 128
  __shared__ float lse[kQ];
  __shared__ int matched[kQ];
  __shared__ float scratch[2];
  float total = 0.f;
  for (int b = 0; b < kB; ++b) {
    if (tid < kQ) {
      const float* lr = logits + (size_t)(b * kQ + tid) * kC1;
      float m = lr[0];
#pragma unroll
      for (int c = 1; c < kC1; ++c) m = fmaxf(m, lr[c]);
      float s = 0.f;
#pragma unroll
      for (int c = 0; c < kC1; ++c) s += __expf(lr[c] - m);
      lse[tid] = m + __logf(s);
      matched[tid] = 0;
    }
    __syncthreads();
    if (tid < kI) matched[idx_q[b * kI + tid]] = 1;
    __syncthreads();

    float fo = 0.f, di = 0.f, cm = 0.f, no = 0.f, nu = 0.f;
    if (tid < kI) {
      int qi = idx_q[b * kI + tid];
      int bq = b * kQ + qi;
      float f = fS[(size_t)bq * kI + tid];
      fo = f + negTot[bq];
      float pp = pS[(size_t)bq * kI + tid];
      di = 1.f - (2.f * pp + 1.f) / (pTot[bq] + (float)cnt[b * kI + tid] + 1.f);
      int fi = firstIdx[b * kI + tid];
      fi = fi < kN ? fi : kN - 1;
      int ci = seg[(size_t)b * kN + fi];
      ci = ci < 0 ? 0 : (ci > kC1 - 2 ? kC1 - 2 : ci);  // clip(·,0,C-1)
      cm = logits[(size_t)bq * kC1 + ci] - lse[qi];
    }
    if (tid < kQ && !matched[tid]) {
      no = logits[(size_t)(b * kQ + tid) * kC1 + (kC1 - 1)] - lse[tid];
      nu = 1.f;
    }
    float foS = reduce128(fo, scratch, tid);
    float diS = reduce128(di, scratch, tid);
    float cmS = reduce128(cm, scratch, tid);
    float noS = reduce128(no, scratch, tid);
    float nuS = reduce128(nu, scratch, tid);

    float focal = foS / ((float)kI * (float)kN);
    float dice  = diS / (float)kI;
    float cem   = -cmS / (float)kI;
    float cen   = -noS / fmaxf(nuS, 1.f);
    total += focal + dice + 2.0f * cem + 0.1f * cen;
    __syncthreads();
  }
  if (tid == 0) out[0] = total * (1.0f / kB);
}

// ---------------------------------------------------------------------------
extern "C" void kernel_launch(void* const* d_in, const int* in_sizes, int n_in,
                              void* d_out, int out_size, void* d_ws, size_t ws_size,
                              hipStream_t stream) {
  const float* pm     = (const float*)d_in[0];  // [B,Q,N]
  const float* logits = (const float*)d_in[1];  // [B,Q,C1]
  const int*   labels = (const int*)d_in[2];    // [B,N]
  const int*   seg    = (const int*)d_in[3];    // [B,N]

  char* w = (char*)d_ws;
  float* fS       = (float*)w; w += (size_t)kB * kQ * kI * 4;
  float* pS       = (float*)w; w += (size_t)kB * kQ * kI * 4;
  float* negTot   = (float*)w; w += (size_t)kB * kQ * 4;
  float* pTot     = (float*)w; w += (size_t)kB * kQ * 4;
  float* costT    = (float*)w; w += (size_t)kB * kI * kQ * 4;
  int*   cnt      = (int*)w;   w += (size_t)kB * kI * 4;
  int*   firstIdx = (int*)w;   w += (size_t)kB * kI * 4;
  int*   idx_q    = (int*)w;   w += (size_t)kB * kI * 4;

  (void)hipMemsetAsync(cnt, 0, (size_t)kB * kI * 4, stream);
  (void)hipMemsetAsync(firstIdx, 0x7F, (size_t)kB * kI * 4, stream);

  prep_kernel<<<dim3(32, kB), 256, 0, stream>>>(labels, cnt, firstIdx);
  bucket_kernel<<<dim3(kQ, kB), 1024, 0, stream>>>(pm, labels, cnt, fS, pS,
                                                   negTot, pTot, costT);
  hungarian_kernel<<<kB, 64, 0, stream>>>(costT, idx_q);
  loss_kernel<<<1, 128, 0, stream>>>(logits, seg, fS, pS, negTot, pTot,
                                     cnt, firstIdx, idx_q, (float*)d_out);
}

// Round 15
// 355.980 us; speedup vs baseline: 1.0965x; 1.0444x over previous
//
#include <hip/hip_runtime.h>
#include <cstdint>
#include <cstddef>

// Problem constants (fixed by setup_inputs)
constexpr int kB  = 2;        // batch
constexpr int kQ  = 100;      // queries
constexpr int kN  = 200000;   // points
constexpr int kI  = 64;       // instances
constexpr int kC1 = 6;        // classes + 1 (no-object)
constexpr int kQP = 128;      // padded column count (cols >= kQ cost 1e30)
constexpr int kPB = 32;       // prep blocks per batch

// ---------------------------------------------------------------------------
// prep v2: per-block PARTIAL histogram/first-idx (plain stores, no global
// atomics, no memset needed). cntPart/fiPart: [kB][kPB][kI].
// ---------------------------------------------------------------------------
__global__ void prep_kernel(const int* __restrict__ labels,
                            int* __restrict__ cntPart, int* __restrict__ fiPart) {
  const int b = blockIdx.y;
  const int tid = threadIdx.x;
  __shared__ int lcnt[kI], lmin[kI];
  if (tid < kI) { lcnt[tid] = 0; lmin[tid] = 0x7FFFFFFF; }
  __syncthreads();
  for (int n = blockIdx.x * blockDim.x + tid; n < kN; n += gridDim.x * blockDim.x) {
    int l = labels[(size_t)b * kN + n] & (kI - 1);
    atomicAdd(&lcnt[l], 1);
    atomicMin(&lmin[l], n);
  }
  __syncthreads();
  if (tid < kI) {
    int o = (b * kPB + blockIdx.x) * kI + tid;
    cntPart[o] = lcnt[tid];
    fiPart[o]  = lmin[tid];
  }
}

// ---------------------------------------------------------------------------
// bucket v4: segmented sums, ONE packed u64 LDS atomic per element
// (hi32 = fi signed scale 2^14, lo32 = pi). cnt summed from partials.
// ---------------------------------------------------------------------------
__global__ __launch_bounds__(1024) void bucket_kernel(
    const float* __restrict__ pm, const int* __restrict__ labels,
    const int* __restrict__ cntPart,
    float* __restrict__ fS, float* __restrict__ pS,
    float* __restrict__ negTot, float* __restrict__ pTot,
    float* __restrict__ costT) {
  const int q = blockIdx.x, b = blockIdx.y;
  const int tid = threadIdx.x;
  const int w = tid >> 6;
  constexpr float kScale = 16384.0f;          // 2^14
  constexpr double kInv  = 1.0 / 16384.0;

  __shared__ unsigned long long lS[16][kI];   // per-wave packed (fi<<32)+pi
  ((unsigned long long*)lS)[tid] = 0ull;      // 16*64 == 1024
  __syncthreads();

  const float4* row4 = (const float4*)(pm + ((size_t)(b * kQ + q)) * kN);
  const int4*   lab4 = (const int4*)(labels + (size_t)b * kN);
  float negAcc = 0.f;
  constexpr int NV4 = kN / 4;

  for (int it = tid; it < NV4; it += 1024) {
    float4 xv = row4[it];
    int4   lv = lab4[it];
#define PROC(x_, l_) do {                                   \
      float x = (x_); int l = (l_) & (kI - 1);              \
      float xc = fminf(fmaxf(x, -60.f), 60.f);              \
      float t  = __expf(-xc);                               \
      float r  = 1.0f / (1.0f + t);   /* sigmoid(x) */      \
      float L  = __logf(1.0f + t);    /* softplus(-x) */    \
      float omp = t * r;              /* 1 - p */           \
      float pos = 0.25f * omp * omp * L;                    \
      float neg = 0.75f * r * r * (L + x);                  \
      int fi = __float2int_rn((pos - neg) * kScale);        \
      int pi = __float2int_rn(r * kScale);                  \
      unsigned long long pk =                               \
        (unsigned long long)(((long long)fi) << 32) +       \
        (unsigned long long)(unsigned int)pi;               \
      atomicAdd(&lS[w][l], pk);                             \
      negAcc += neg;                                        \
    } while (0)
    PROC(xv.x, lv.x); PROC(xv.y, lv.y); PROC(xv.z, lv.z); PROC(xv.w, lv.w);
#undef PROC
  }
  __syncthreads();

  __shared__ float ffS[kI], fpS[kI];
  if (tid < kI) {
    long long fsum = 0, psum = 0;
    for (int ww = 0; ww < 16; ++ww) {
      unsigned long long s = lS[ww][tid];
      fsum += (int)(s >> 32);                 // two's-complement hi word
      psum += (long long)(s & 0xFFFFFFFFull);
    }
    ffS[tid] = (float)((double)fsum * kInv);
    fpS[tid] = (float)((double)psum * kInv);
  }
  for (int off = 32; off; off >>= 1) negAcc += __shfl_down(negAcc, off);
  __shared__ float wsum[16];
  if ((tid & 63) == 0) wsum[w] = negAcc;
  __syncthreads();
  __shared__ float s_negTot, s_pTot;
  if (tid == 0) {
    float s = 0.f;
    for (int ww = 0; ww < 16; ++ww) s += wsum[ww];
    s_negTot = s;
  }
  if (tid < kI) {
    float vv = fpS[tid];
    for (int off = 32; off; off >>= 1) vv += __shfl_down(vv, off);
    if (tid == 0) s_pTot = vv;
  }
  __syncthreads();

  if (tid < kI) {
    int cv = 0;
    for (int blk = 0; blk < kPB; ++blk)
      cv += cntPart[(b * kPB + blk) * kI + tid];
    float f = ffS[tid], pp = fpS[tid];
    int bq = b * kQ + q;
    fS[(size_t)bq * kI + tid] = f;
    pS[(size_t)bq * kI + tid] = pp;
    float cf = (f + s_negTot) * (1.0f / kN);
    float cd = 1.0f - (2.0f * pp + 1.0f) / (s_pTot + (float)cv + 1.0f);
    costT[(size_t)(b * kI + tid) * kQ + q] = cf + cd;
    if (tid == 0) { negTot[bq] = s_negTot; pTot[bq] = s_pTot; }
  }
}

// ---------------------------------------------------------------------------
// Hungarian v14 — r14 machinery (full-f32 SAP; f32-select + exact-f64
// augrowred) with: interleaved column ownership (lane owns cols 2L, 2L+1
// -> one ds_read_b64 per row fetch), float4 init scan, PARALLEL greedy
// claim (LDS atomicMin: winner = smallest row index, provably identical
// to the serial row-order loop), ballot rowM.
// CS lesson stands (v5-v7, v10): no dual warm starts.
// ---------------------------------------------------------------------------
template<int CTRL>
__device__ __forceinline__ int dpp_mov(int x) {
  return __builtin_amdgcn_update_dpp(x, x, CTRL, 0xF, 0xF, false);
}
template<int CTRL>
__device__ __forceinline__ float dpp_minf(float a) {
  int o = dpp_mov<CTRL>(__float_as_int(a));
  return fminf(a, __int_as_float(o));
}
__device__ __forceinline__ double rl64(double x, int l) {
  int lo = __builtin_amdgcn_readlane(__double2loint(x), l);
  int hi = __builtin_amdgcn_readlane(__double2hiint(x), l);
  return __hiloint2double(hi, lo);
}
__device__ __forceinline__ float rlf(float x, int l) {
  return __int_as_float(__builtin_amdgcn_readlane(__float_as_int(x), l));
}
__device__ __forceinline__ float packF(float v, int cid) {
  int bb = __float_as_int(v);
  bb = (bb & ~0x7F) | cid;
  return __int_as_float(bb);
}
__device__ __forceinline__ float maskF(float v) {          // id bits -> 0
  return __int_as_float(__float_as_int(v) & ~0x7F);
}
// two-smallest combine on packed f32 (value order; ids ride in low bits)
__device__ __forceinline__ void comb2f(float& m1, float& m2, float o1, float o2) {
  float lo = fminf(m1, o1);
  float hi = fmaxf(m1, o1);
  m2 = fminf(hi, fminf(m2, o2));
  m1 = lo;
}
template<int CTRL>
__device__ __forceinline__ void dpp_comb2f(float& m1, float& m2) {
  float o1 = __int_as_float(dpp_mov<CTRL>(__float_as_int(m1)));
  float o2 = __int_as_float(dpp_mov<CTRL>(__float_as_int(m2)));
  comb2f(m1, m2, o1, o2);
}

__global__ void hungarian_kernel(const float* __restrict__ costT,
                                 int* __restrict__ idx_q) {
  const int b = blockIdx.x;
  const int lane = threadIdx.x;  // 64 threads = 1 wave
  __shared__ float costL[kI * kQP];
  __shared__ int claim[kQP];
  for (int t = lane; t < kI * kQP; t += 64) {
    int row = t >> 7, col = t & (kQP - 1);
    costL[t] = (col < kQ) ? costT[(size_t)b * kI * kQ + row * kQ + col] : 1e30f;
  }
  claim[lane] = 127;
  claim[lane + 64] = 127;
  __syncthreads();

  const int col0 = 2 * lane, col1 = 2 * lane + 1;  // owned columns
  double v0 = 0.0, v1 = 0.0;     // v[col0], v[col1]
  int p0 = 0, p1 = 0;            // matched row (1-based) of col0, col1

  // --- JV init: u[row]=row min (float4 scan, first-index tie-break) -------
  double m = 1e18; int jm = 0;
  {
    const float4* r4 = (const float4*)&costL[lane * kQP];
    for (int k4 = 0; k4 < kQ / 4; ++k4) {
      float4 c = r4[k4];
      int k = 4 * k4;
      if ((double)c.x < m) { m = (double)c.x; jm = k; }
      if ((double)c.y < m) { m = (double)c.y; jm = k + 1; }
      if ((double)c.z < m) { m = (double)c.z; jm = k + 2; }
      if ((double)c.w < m) { m = (double)c.w; jm = k + 3; }
    }
  }
  double u_r = m;                             // u[lane+1]

  // --- parallel greedy claim: winner(col) = smallest row index ------------
  atomicMin(&claim[jm], lane);
  __syncthreads();
  unsigned long long rowM = __ballot(claim[jm] == lane);
  {
    int w0 = claim[col0], w1 = claim[col1];
    p0 = (w0 < 64) ? w0 + 1 : 0;
    p1 = (w1 < 64) ? w1 + 1 : 0;
  }

  // --- LAPJV augmenting row reduction (2 passes; f32 select + exact f64) ---
  unsigned long long pool = ~rowM;            // unmatched rows (bit r = row r+1)
  unsigned long long leftover = 0ull;
  for (int pass = 0; pass < 2; ++pass) {
    unsigned long long next = 0ull;
    unsigned long long cur = pool;
    while (cur) {
      int i = __builtin_ctzll(cur) + 1;       // row, 1-based
      cur &= cur - 1;
      float2 cc = *(const float2*)&costL[(i - 1) * kQP + col0];
      double e0 = (double)cc.x - v0;
      double e1 = (double)cc.y - v1;          // padded cols ~1e30
      float pf0 = packF((float)e0, col0);
      float pf1 = packF((float)e1, col1);
      float m1 = fminf(pf0, pf1), m2 = fmaxf(pf0, pf1);
      dpp_comb2f<0xB1>(m1, m2);               // xor 1
      dpp_comb2f<0x4E>(m1, m2);               // xor 2
      dpp_comb2f<0x141>(m1, m2);              // xor 4
      dpp_comb2f<0x140>(m1, m2);              // xor 8
      float a1 = rlf(m1, 0),  a2 = rlf(m2, 0);
      { float b1 = rlf(m1, 16), b2 = rlf(m2, 16); comb2f(a1, a2, b1, b2); }
      { float b1 = rlf(m1, 32), b2 = rlf(m2, 32); comb2f(a1, a2, b1, b2); }
      { float b1 = rlf(m1, 48), b2 = rlf(m2, 48); comb2f(a1, a2, b1, b2); }
      int cid1 = __builtin_amdgcn_readfirstlane(__float_as_int(a1) & 0x7F);
      int cid2 = __builtin_amdgcn_readfirstlane(__float_as_int(a2) & 0x7F);
      int L1 = cid1 >> 1; bool sW = cid1 & 1;
      int L2 = cid2 >> 1; bool sW2 = cid2 & 1;
      double min1 = sW  ? rl64(e1, L1) : rl64(e0, L1);   // EXACT values
      double min2 = sW2 ? rl64(e1, L2) : rl64(e0, L2);
      double dv = min2 - min1;
      u_r = (lane == i - 1) ? min2 : u_r;     // u[i] = second minimum
      int i0 = sW ? __builtin_amdgcn_readlane(p1, L1)
                  : __builtin_amdgcn_readlane(p0, L1);
      bool mine0 = (!sW) && (lane == L1);
      bool mine1 = sW && (lane == L1);
      p0 = mine0 ? i : p0;  v0 -= mine0 ? dv : 0.0;
      p1 = mine1 ? i : p1;  v1 -= mine1 ? dv : 0.0;
      if (i0 != 0) {                          // kicked row -> later pass / SAP
        if (pass == 0) next |= 1ull << (i0 - 1);
        else           leftover |= 1ull << (i0 - 1);
      }
    }
    pool = next;
  }
  leftover |= pool;                           // (pool empty after pass 1)

  // --- exact SAP for leftover rows (full-f32 packed round, b64 row fetch) --
  const float SENT = packF(1e30f, 127);
  float u_f  = (float)u_r;
  float v0f  = (float)v0;
  float v1f  = (float)v1;
  for (int i = 1; i <= kI; ++i) {
    if (!((leftover >> (i - 1)) & 1ull)) continue;
    float minv0 = SENT, minv1 = SENT;   // packed (value | col id)
    int way0 = 0, way1 = 0;
    bool used0 = false, used1 = false;
    bool onpath = (lane == i - 1);
    int j0 = 0, j1 = 0;
    float2 cc = *(const float2*)&costL[(i - 1) * kQP + col0];
    float c0 = cc.x, c1 = cc.y;
    float ui0 = rlf(u_f, i - 1);
    for (int guard = 0; guard < 2 * kQ; ++guard) {
      float pk0 = packF(c0 - ui0 - v0f, col0);
      bool up0 = (!used0) && (pk0 < minv0);
      minv0 = up0 ? pk0 : minv0;
      way0  = up0 ? j0 : way0;
      float pk1 = packF(c1 - ui0 - v1f, col1);
      bool up1 = (!used1) && (pk1 < minv1);
      minv1 = up1 ? pk1 : minv1;
      way1  = up1 ? j0 : way1;
      // argmin butterfly on packed values (used slots already SENT)
      float bm = fminf(minv0, minv1);
      bm = dpp_minf<0xB1>(bm);    // xor 1
      bm = dpp_minf<0x4E>(bm);    // xor 2
      bm = dpp_minf<0x141>(bm);   // xor 4
      bm = dpp_minf<0x140>(bm);   // xor 8
      float g = fminf(fminf(rlf(bm, 0), rlf(bm, 16)),
                      fminf(rlf(bm, 32), rlf(bm, 48)));
      int gi = __builtin_amdgcn_readfirstlane(__float_as_int(g));
      int cid = gi & 0x7F;
      float delta = __int_as_float(gi & ~0x7F);   // quantized min value
      const int  L = cid >> 1;
      const bool s = cid & 1;
      int r1 = s ? __builtin_amdgcn_readlane(p1, L)
                 : __builtin_amdgcn_readlane(p0, L);
      // prefetch next row while updating duals
      int i0n = (r1 > 0) ? r1 : 1;
      float2 cn = *(const float2*)&costL[(i0n - 1) * kQP + col0];

      u_f += onpath ? delta : 0.f;
      v0f -= used0 ? delta : 0.f;
      v1f -= used1 ? delta : 0.f;
      minv0 = used0 ? minv0 : packF(maskF(minv0) - delta, col0);
      minv1 = used1 ? minv1 : packF(maskF(minv1) - delta, col1);
      bool w0 = (!s) && (lane == L);
      bool w1 = s && (lane == L);
      used0 = used0 || w0;
      used1 = used1 || w1;
      minv0 = w0 ? SENT : minv0;
      minv1 = w1 ? SENT : minv1;
      j1 = cid + 1;                 // 1-based col id for augment chain

      if (r1 == 0) break;           // free column reached
      onpath = onpath || (lane == r1 - 1);
      ui0 = rlf(u_f, r1 - 1);       // prefetched for next round
      j0 = j1;
      c0 = cn.x;
      c1 = cn.y;
    }
    // augment along way-chain (all indices/values uniform)
    int jc = j1;
    while (jc) {
      int Lc = (jc - 1) >> 1, sc = (jc - 1) & 1;
      int jw = sc ? __builtin_amdgcn_readlane(way1, Lc)
                  : __builtin_amdgcn_readlane(way0, Lc);
      int pw;
      if (jw == 0) pw = i;
      else {
        int Lw = (jw - 1) >> 1, sw = (jw - 1) & 1;
        pw = sw ? __builtin_amdgcn_readlane(p1, Lw)
                : __builtin_amdgcn_readlane(p0, Lw);
      }
      bool w0 = (!sc) && (lane == Lc);
      bool w1 = sc && (lane == Lc);
      p0 = w0 ? pw : p0;
      p1 = w1 ? pw : p1;
      jc = jw;
    }
  }
  if (col0 < kQ && p0 > 0) idx_q[b * kI + (p0 - 1)] = col0;
  if (col1 < kQ && p1 > 0) idx_q[b * kI + (p1 - 1)] = col1;
}

// ---------------------------------------------------------------------------
// final loss from bucket sums + matching (cnt/firstIdx from partials)
// ---------------------------------------------------------------------------
__device__ __forceinline__ float reduce128(float v, float* scratch, int tid) {
  for (int off = 32; off; off >>= 1) v += __shfl_down(v, off);
  __syncthreads();
  if ((tid & 63) == 0) scratch[tid >> 6] = v;
  __syncthreads();
  return scratch[0] + scratch[1];
}

__global__ void loss_kernel(const float* __restrict__ logits, const int* __restrict__ seg,
                            const float* __restrict__ fS, const float* __restrict__ pS,
                            const float* __restrict__ negTot, const float* __restrict__ pTot,
                            const int* __restrict__ cntPart, const int* __restrict__ fiPart,
                            const int* __restrict__ idx_q, float* __restrict__ out) {
  const int tid = threadIdx.x;  // 128
  __shared__ float lse[kQ];
  __shared__ int matched[kQ];
  __shared__ float scratch[2];
  float total = 0.f;
  for (int b = 0; b < kB; ++b) {
    if (tid < kQ) {
      const float* lr = logits + (size_t)(b * kQ + tid) * kC1;
      float m = lr[0];
#pragma unroll
      for (int c = 1; c < kC1; ++c) m = fmaxf(m, lr[c]);
      float s = 0.f;
#pragma unroll
      for (int c = 0; c < kC1; ++c) s += __expf(lr[c] - m);
      lse[tid] = m + __logf(s);
      matched[tid] = 0;
    }
    __syncthreads();
    if (tid < kI) matched[idx_q[b * kI + tid]] = 1;
    __syncthreads();

    float fo = 0.f, di = 0.f, cm = 0.f, no = 0.f, nu = 0.f;
    if (tid < kI) {
      int cv = 0, fi = 0x7FFFFFFF;
      for (int blk = 0; blk < kPB; ++blk) {
        int o = (b * kPB + blk) * kI + tid;
        cv += cntPart[o];
        fi = min(fi, fiPart[o]);
      }
      int qi = idx_q[b * kI + tid];
      int bq = b * kQ + qi;
      float f = fS[(size_t)bq * kI + tid];
      fo = f + negTot[bq];
      float pp = pS[(size_t)bq * kI + tid];
      di = 1.f - (2.f * pp + 1.f) / (pTot[bq] + (float)cv + 1.f);
      fi = fi < kN ? fi : kN - 1;
      int ci = seg[(size_t)b * kN + fi];
      ci = ci < 0 ? 0 : (ci > kC1 - 2 ? kC1 - 2 : ci);  // clip(·,0,C-1)
      cm = logits[(size_t)bq * kC1 + ci] - lse[qi];
    }
    if (tid < kQ && !matched[tid]) {
      no = logits[(size_t)(b * kQ + tid) * kC1 + (kC1 - 1)] - lse[tid];
      nu = 1.f;
    }
    float foS = reduce128(fo, scratch, tid);
    float diS = reduce128(di, scratch, tid);
    float cmS = reduce128(cm, scratch, tid);
    float noS = reduce128(no, scratch, tid);
    float nuS = reduce128(nu, scratch, tid);

    float focal = foS / ((float)kI * (float)kN);
    float dice  = diS / (float)kI;
    float cem   = -cmS / (float)kI;
    float cen   = -noS / fmaxf(nuS, 1.f);
    total += focal + dice + 2.0f * cem + 0.1f * cen;
    __syncthreads();
  }
  if (tid == 0) out[0] = total * (1.0f / kB);
}

// ---------------------------------------------------------------------------
extern "C" void kernel_launch(void* const* d_in, const int* in_sizes, int n_in,
                              void* d_out, int out_size, void* d_ws, size_t ws_size,
                              hipStream_t stream) {
  const float* pm     = (const float*)d_in[0];  // [B,Q,N]
  const float* logits = (const float*)d_in[1];  // [B,Q,C1]
  const int*   labels = (const int*)d_in[2];    // [B,N]
  const int*   seg    = (const int*)d_in[3];    // [B,N]

  char* w = (char*)d_ws;
  float* fS       = (float*)w; w += (size_t)kB * kQ * kI * 4;
  float* pS       = (float*)w; w += (size_t)kB * kQ * kI * 4;
  float* negTot   = (float*)w; w += (size_t)kB * kQ * 4;
  float* pTot     = (float*)w; w += (size_t)kB * kQ * 4;
  float* costT    = (float*)w; w += (size_t)kB * kI * kQ * 4;
  int*   cntPart  = (int*)w;   w += (size_t)kB * kPB * kI * 4;
  int*   fiPart   = (int*)w;   w += (size_t)kB * kPB * kI * 4;
  int*   idx_q    = (int*)w;   w += (size_t)kB * kI * 4;

  prep_kernel<<<dim3(kPB, kB), 256, 0, stream>>>(labels, cntPart, fiPart);
  bucket_kernel<<<dim3(kQ, kB), 1024, 0, stream>>>(pm, labels, cntPart, fS, pS,
                                                   negTot, pTot, costT);
  hungarian_kernel<<<kB, 64, 0, stream>>>(costT, idx_q);
  loss_kernel<<<1, 128, 0, stream>>>(logits, seg, fS, pS, negTot, pTot,
                                     cntPart, fiPart, idx_q, (float*)d_out);
}